// Round 1
// baseline (600.561 us; speedup 1.0000x reference)
//
#include <hip/hip_runtime.h>

#define N_NODES 100000
#define N_EVENTS 100000
#define D 128

// ---- workspace layout (bytes) ----
#define SUMS_BYTES (N_NODES * 384 * 4)            // 153,600,000
#define OFF_CNT    SUMS_BYTES
#define OFF_LAST   (OFF_CNT + N_NODES * 4)
#define OFF_WIH    (OFF_LAST + N_NODES * 4)       // 154,400,000
#define OFF_WHH    (OFF_WIH + 384 * 512 * 2)
#define ZERO_F4    ((SUMS_BYTES + N_NODES * 8) / 16)   // 9,650,000 float4

typedef __attribute__((ext_vector_type(8))) short bf16x8;
typedef __attribute__((ext_vector_type(4))) float f32x4;

__device__ inline short f2bf(float x) {
    unsigned u = __float_as_uint(x);
    u = (u + 0x7FFFu + ((u >> 16) & 1u)) >> 16;
    return (short)u;
}

// ---- kernel 1: zero accumulators, convert weights to bf16 ----
__global__ __launch_bounds__(256) void k_init(float4* __restrict__ z,
                                              const float* __restrict__ wih,
                                              const float* __restrict__ whh,
                                              short* __restrict__ wihb,
                                              short* __restrict__ whhb) {
    int i = blockIdx.x * blockDim.x + threadIdx.x;
    int stride = gridDim.x * blockDim.x;
    for (int j = i; j < ZERO_F4; j += stride) z[j] = make_float4(0.f, 0.f, 0.f, 0.f);
    for (int j = i; j < 384 * 512; j += stride) wihb[j] = f2bf(wih[j]);
    for (int j = i; j < 384 * 128; j += stride) whhb[j] = f2bf(whh[j]);
}

// ---- kernel 2: per-event message scatter (blocks 1..3 of the message) ----
__global__ __launch_bounds__(128) void k_scatter(const float* __restrict__ mem,
                                                 const int* __restrict__ lu,
                                                 const int* __restrict__ src,
                                                 const int* __restrict__ dst,
                                                 const int* __restrict__ t,
                                                 const float* __restrict__ raw,
                                                 const float* __restrict__ tw,
                                                 const float* __restrict__ tb,
                                                 float* __restrict__ sums,
                                                 unsigned* __restrict__ cnt,
                                                 int* __restrict__ lastmax) {
    const int e = blockIdx.x;
    const int i = threadIdx.x;
    const int s = src[e], d = dst[e], te = t[e];
    const float ms = mem[s * D + i];
    const float md = mem[d * D + i];
    const float r  = raw[e * D + i];
    const float wi = tw[i], bi = tb[i];
    // match numpy: separate mul + add rounding (NO fma) before cos
    const float trs = (float)(te - lu[s]);
    const float trd = (float)(te - lu[d]);
    const float encs = cosf(__fadd_rn(__fmul_rn(trs, wi), bi));
    const float encd = cosf(__fadd_rn(__fmul_rn(trd, wi), bi));
    // message to node s: [mem[s] (analytic), mem[d], raw, enc_s]
    atomicAdd(&sums[s * 384 + i],        md);
    atomicAdd(&sums[s * 384 + 128 + i], r);
    atomicAdd(&sums[s * 384 + 256 + i], encs);
    // message to node d: [mem[d] (analytic), mem[s], raw, enc_d]
    atomicAdd(&sums[d * 384 + i],        ms);
    atomicAdd(&sums[d * 384 + 128 + i], r);
    atomicAdd(&sums[d * 384 + 256 + i], encd);
    if (i == 0) {
        atomicAdd(&cnt[s], 1u);
        atomicAdd(&cnt[d], 1u);
        atomicMax(&lastmax[s], te);
        atomicMax(&lastmax[d], te);
    }
}

// ---- kernel 3: fused GEMM (gx = aggr @ w_ih^T, gh = mem @ w_hh^T) + GRU ----
// BM=32 nodes/block, 256 threads (4 waves). Wave w owns gate-column groups
// q in {2w, 2w+1}; jt rows {q, q+8, q+16} so the (r,z,n) triple is wave-local.
__global__ __launch_bounds__(256) void k_gemm_gru(const float* __restrict__ mem,
                                                  const float* __restrict__ sums,
                                                  const unsigned* __restrict__ cnt,
                                                  const short* __restrict__ wih,
                                                  const short* __restrict__ whh,
                                                  const float* __restrict__ bih,
                                                  const float* __restrict__ bhh,
                                                  float* __restrict__ out) {
    __shared__ short sA[32 * 512];   // aggr, bf16, XOR-swizzled
    __shared__ short sM[32 * 128];   // memory, bf16, XOR-swizzled
    const int tid = threadIdx.x;
    const int node0 = blockIdx.x * 32;

    // stage aggr[32][512]: cols 0..127 = (cnt>0 ? mem : 0); cols 128..511 = sums/max(cnt,1)
#pragma unroll
    for (int it = 0; it < 8; ++it) {
        int c = tid + (it << 8);
        int row = c >> 6, cc = c & 63;
        int node = node0 + row;
        float4 x0, x1;
        float scale;
        if (cc < 16) {
            const float4* p = (const float4*)(mem + node * D + cc * 8);
            x0 = p[0]; x1 = p[1];
            scale = (cnt[node] > 0u) ? 1.f : 0.f;
        } else {
            const float4* p = (const float4*)(sums + node * 384 + (cc - 16) * 8);
            x0 = p[0]; x1 = p[1];
            unsigned c0 = cnt[node];
            scale = 1.f / (float)(c0 > 1u ? c0 : 1u);
        }
        bf16x8 h;
        h[0] = f2bf(x0.x * scale); h[1] = f2bf(x0.y * scale);
        h[2] = f2bf(x0.z * scale); h[3] = f2bf(x0.w * scale);
        h[4] = f2bf(x1.x * scale); h[5] = f2bf(x1.y * scale);
        h[6] = f2bf(x1.z * scale); h[7] = f2bf(x1.w * scale);
        int boff = row * 1024 + ((cc * 16) ^ ((row & 7) << 4));
        *(bf16x8*)((char*)sA + boff) = h;
    }
    // stage mem[32][128] bf16
#pragma unroll
    for (int it = 0; it < 2; ++it) {
        int c = tid + (it << 8);
        int row = c >> 4, cc = c & 15;
        int node = node0 + row;
        const float4* p = (const float4*)(mem + node * D + cc * 8);
        float4 x0 = p[0], x1 = p[1];
        bf16x8 h;
        h[0] = f2bf(x0.x); h[1] = f2bf(x0.y); h[2] = f2bf(x0.z); h[3] = f2bf(x0.w);
        h[4] = f2bf(x1.x); h[5] = f2bf(x1.y); h[6] = f2bf(x1.z); h[7] = f2bf(x1.w);
        int boff = row * 256 + ((cc * 16) ^ ((row & 7) << 4));
        *(bf16x8*)((char*)sM + boff) = h;
    }
    __syncthreads();

    const int l = tid & 63, w = tid >> 6;
    const int lr = l & 15, lk = l >> 4;
    const int q0 = 2 * w;
    const int jts[6] = {q0, q0 + 1, q0 + 8, q0 + 9, q0 + 16, q0 + 17};

    f32x4 accX[2][6], accH[2][6];
#pragma unroll
    for (int mt = 0; mt < 2; ++mt)
#pragma unroll
        for (int j = 0; j < 6; ++j) {
            accX[mt][j] = (f32x4){0.f, 0.f, 0.f, 0.f};
            accH[mt][j] = (f32x4){0.f, 0.f, 0.f, 0.f};
        }

    const int swz0 = (lr & 7) << 4;
    // gx: K=512 over sA / wih
#pragma unroll 4
    for (int kk = 0; kk < 512; kk += 32) {
        int col = kk * 2 + lk * 16;
        bf16x8 a0 = *(const bf16x8*)((const char*)sA + lr * 1024 + (col ^ swz0));
        bf16x8 a1 = *(const bf16x8*)((const char*)sA + (16 + lr) * 1024 + (col ^ swz0));
#pragma unroll
        for (int j = 0; j < 6; ++j) {
            bf16x8 b = *(const bf16x8*)(wih + (jts[j] * 16 + lr) * 512 + kk + lk * 8);
            accX[0][j] = __builtin_amdgcn_mfma_f32_16x16x32_bf16(a0, b, accX[0][j], 0, 0, 0);
            accX[1][j] = __builtin_amdgcn_mfma_f32_16x16x32_bf16(a1, b, accX[1][j], 0, 0, 0);
        }
    }
    // gh: K=128 over sM / whh
#pragma unroll
    for (int kk = 0; kk < 128; kk += 32) {
        int col = kk * 2 + lk * 16;
        bf16x8 a0 = *(const bf16x8*)((const char*)sM + lr * 256 + (col ^ swz0));
        bf16x8 a1 = *(const bf16x8*)((const char*)sM + (16 + lr) * 256 + (col ^ swz0));
#pragma unroll
        for (int j = 0; j < 6; ++j) {
            bf16x8 b = *(const bf16x8*)(whh + (jts[j] * 16 + lr) * 128 + kk + lk * 8);
            accH[0][j] = __builtin_amdgcn_mfma_f32_16x16x32_bf16(a0, b, accH[0][j], 0, 0, 0);
            accH[1][j] = __builtin_amdgcn_mfma_f32_16x16x32_bf16(a1, b, accH[1][j], 0, 0, 0);
        }
    }

    // epilogue: GRU gates. C layout: col = l&15, row = (l>>4)*4 + reg.
#pragma unroll
    for (int qi = 0; qi < 2; ++qi) {
        const int q = q0 + qi;
        const int jcol = q * 16 + lr;
        const float bxr = bih[jcol],       bhr = bhh[jcol];
        const float bxz = bih[128 + jcol], bhz = bhh[128 + jcol];
        const float bxn = bih[256 + jcol], bhn = bhh[256 + jcol];
#pragma unroll
        for (int mt = 0; mt < 2; ++mt) {
#pragma unroll
            for (int i = 0; i < 4; ++i) {
                const int node = node0 + mt * 16 + lk * 4 + i;
                const float xr = accX[mt][qi][i] + bxr,     hr = accH[mt][qi][i] + bhr;
                const float xz = accX[mt][2 + qi][i] + bxz, hz = accH[mt][2 + qi][i] + bhz;
                const float xn = accX[mt][4 + qi][i] + bxn, hn = accH[mt][4 + qi][i] + bhn;
                const float rg = 1.f / (1.f + expf(-(xr + hr)));
                const float zg = 1.f / (1.f + expf(-(xz + hz)));
                const float ng = tanhf(xn + rg * hn);
                const float mo = mem[node * D + jcol];
                out[node * D + jcol] = (1.f - zg) * ng + zg * mo;
            }
        }
    }
}

// ---- kernel 4: last_update writeout (as float values) ----
__global__ __launch_bounds__(256) void k_last(const int* __restrict__ lastmax,
                                              float* __restrict__ o) {
    int n = blockIdx.x * blockDim.x + threadIdx.x;
    if (n < N_NODES) o[n] = (float)lastmax[n];
}

extern "C" void kernel_launch(void* const* d_in, const int* in_sizes, int n_in,
                              void* d_out, int out_size, void* d_ws, size_t ws_size,
                              hipStream_t stream) {
    const float* memory      = (const float*)d_in[0];
    const int*   last_update = (const int*)d_in[1];
    const int*   src         = (const int*)d_in[2];
    const int*   dst         = (const int*)d_in[3];
    const int*   t           = (const int*)d_in[4];
    const float* raw_msg     = (const float*)d_in[5];
    const float* time_w      = (const float*)d_in[6];
    const float* time_b      = (const float*)d_in[7];
    const float* w_ih        = (const float*)d_in[8];
    const float* w_hh        = (const float*)d_in[9];
    const float* b_ih        = (const float*)d_in[10];
    const float* b_hh        = (const float*)d_in[11];

    float* out = (float*)d_out;
    char* ws = (char*)d_ws;
    float*    sums    = (float*)(ws);
    unsigned* cnt     = (unsigned*)(ws + OFF_CNT);
    int*      lastmax = (int*)(ws + OFF_LAST);
    short*    wihb    = (short*)(ws + OFF_WIH);
    short*    whhb    = (short*)(ws + OFF_WHH);

    k_init<<<2048, 256, 0, stream>>>((float4*)ws, w_ih, w_hh, wihb, whhb);
    k_scatter<<<N_EVENTS, 128, 0, stream>>>(memory, last_update, src, dst, t,
                                            raw_msg, time_w, time_b,
                                            sums, cnt, lastmax);
    k_gemm_gru<<<N_NODES / 32, 256, 0, stream>>>(memory, sums, cnt, wihb, whhb,
                                                 b_ih, b_hh, out);
    k_last<<<(N_NODES + 255) / 256, 256, 0, stream>>>(lastmax, out + N_NODES * D);
}

// Round 2
// 447.649 us; speedup vs baseline: 1.3416x; 1.3416x over previous
//
#include <hip/hip_runtime.h>

#define N_NODES 100000
#define N_EVENTS 100000
#define D 128
#define KTOT 640
#define NP 512
#define BM 128

// ---- workspace layout (bytes) ----
#define SUMS_BYTES (N_NODES * 384 * 4)            // 153,600,000
#define OFF_CNT    SUMS_BYTES
#define OFF_LAST   (OFF_CNT + N_NODES * 4)
#define OFF_BP     (OFF_LAST + N_NODES * 4)       // 154,400,000 ; Bp = 512*640*2 = 655,360 B
#define ZERO_F4    ((SUMS_BYTES + N_NODES * 8) / 16)   // 9,650,000 float4

typedef __attribute__((ext_vector_type(8))) short bf16x8;
typedef __attribute__((ext_vector_type(4))) float f32x4;

__device__ __forceinline__ short f2bf(float x) {
    unsigned u = __float_as_uint(x);
    u = (u + 0x7FFFu + ((u >> 16) & 1u)) >> 16;
    return (short)u;
}

// ---- kernel 1: zero accumulators, build packed weight matrix Bp[512][640] bf16 ----
// Bp cols (n): 0-127 -> r (wih rows 0-127 | whh rows 0-127), 128-255 -> z,
// 256-383 -> xn (wih rows 256-383, k<512 only), 384-511 -> hn (whh rows 256-383, k>=512 only)
__global__ __launch_bounds__(256) void k_init(float4* __restrict__ z,
                                              const float* __restrict__ wih,
                                              const float* __restrict__ whh,
                                              short* __restrict__ bp) {
    int i = blockIdx.x * blockDim.x + threadIdx.x;
    int stride = gridDim.x * blockDim.x;
    for (int j = i; j < ZERO_F4; j += stride) z[j] = make_float4(0.f, 0.f, 0.f, 0.f);
    for (int j = i; j < NP * KTOT; j += stride) {
        int n = j / KTOT, k = j - n * KTOT;
        float v = 0.f;
        if (n < 384) {
            if (k < 512) v = wih[n * 512 + k];
            else if (n < 256) v = whh[n * 128 + (k - 512)];
        } else if (k >= 512) {
            v = whh[(n - 128) * 128 + (k - 512)];
        }
        bp[j] = f2bf(v);
    }
}

// ---- kernel 2: per-event message scatter (blocks 1..3 of the message) ----
__global__ __launch_bounds__(128) void k_scatter(const float* __restrict__ mem,
                                                 const int* __restrict__ lu,
                                                 const int* __restrict__ src,
                                                 const int* __restrict__ dst,
                                                 const int* __restrict__ t,
                                                 const float* __restrict__ raw,
                                                 const float* __restrict__ tw,
                                                 const float* __restrict__ tb,
                                                 float* __restrict__ sums,
                                                 unsigned* __restrict__ cnt,
                                                 int* __restrict__ lastmax) {
    const int e = blockIdx.x;
    const int i = threadIdx.x;
    const int s = src[e], d = dst[e], te = t[e];
    const float ms = mem[s * D + i];
    const float md = mem[d * D + i];
    const float r  = raw[e * D + i];
    const float wi = tw[i], bi = tb[i];
    // match numpy: separate mul + add rounding (NO fma) before cos
    const float trs = (float)(te - lu[s]);
    const float trd = (float)(te - lu[d]);
    const float encs = cosf(__fadd_rn(__fmul_rn(trs, wi), bi));
    const float encd = cosf(__fadd_rn(__fmul_rn(trd, wi), bi));
    atomicAdd(&sums[s * 384 + i],        md);
    atomicAdd(&sums[s * 384 + 128 + i], r);
    atomicAdd(&sums[s * 384 + 256 + i], encs);
    atomicAdd(&sums[d * 384 + i],        ms);
    atomicAdd(&sums[d * 384 + 128 + i], r);
    atomicAdd(&sums[d * 384 + 256 + i], encd);
    if (i == 0) {
        atomicAdd(&cnt[s], 1u);
        atomicAdd(&cnt[d], 1u);
        atomicMax(&lastmax[s], te);
        atomicMax(&lastmax[d], te);
    }
}

// ---- kernel 3 helpers ----
// A' cols (k): 0-127 = mem * 1{cnt>0}; 128-511 = sums/max(cnt,1); 512-639 = mem.
// Chunk c covers k-cols [c*64, c*64+64): c<2 -> mem_ind, 2<=c<8 -> sums, c>=8 -> mem.
__device__ __forceinline__ void stage_load(const float* __restrict__ mem,
                                           const float* __restrict__ sums,
                                           int node0, int row_, int cg, int c, float4* v) {
#pragma unroll
    for (int s = 0; s < 2; ++s) {
        int row = row_ + s * 64;
        int node = node0 + row;
        int nc = node < N_NODES ? node : N_NODES - 1;
        const float* p;
        if (c < 2)      p = mem + nc * D + c * 64 + cg * 8;
        else if (c < 8) p = sums + nc * 384 + (c * 64 - 128) + cg * 8;
        else            p = mem + nc * D + (c - 8) * 64 + cg * 8;
        v[2 * s]     = *(const float4*)p;
        v[2 * s + 1] = *(const float4*)(p + 4);
    }
}

__device__ __forceinline__ void stage_write(short* __restrict__ sAbuf,
                                            const float* __restrict__ sInd,
                                            const float* __restrict__ sInv,
                                            int row_, int cg, int c, const float4* v) {
#pragma unroll
    for (int s = 0; s < 2; ++s) {
        int row = row_ + s * 64;
        float scale = (c < 2) ? sInd[row] : (c < 8 ? sInv[row] : 1.f);
        float4 x0 = v[2 * s], x1 = v[2 * s + 1];
        bf16x8 h;
        h[0] = f2bf(x0.x * scale); h[1] = f2bf(x0.y * scale);
        h[2] = f2bf(x0.z * scale); h[3] = f2bf(x0.w * scale);
        h[4] = f2bf(x1.x * scale); h[5] = f2bf(x1.y * scale);
        h[6] = f2bf(x1.z * scale); h[7] = f2bf(x1.w * scale);
        *(bf16x8*)((char*)sAbuf + row * 128 + ((cg * 16) ^ ((row & 7) << 4))) = h;
    }
}

__device__ __forceinline__ void mfma_chunk(const short* __restrict__ sAbuf,
                                           int lr, int lk, int swz,
                                           const short* __restrict__ bR,
                                           const short* __restrict__ bZ,
                                           const short* __restrict__ bN, int kk0,
                                           f32x4* accR, f32x4* accZ, f32x4* accN) {
#pragma unroll
    for (int k2 = 0; k2 < 2; ++k2) {
        bf16x8 a[8];
#pragma unroll
        for (int mt = 0; mt < 8; ++mt)
            a[mt] = *(const bf16x8*)((const char*)sAbuf + (mt * 16 + lr) * 128 +
                                     ((k2 * 64 + lk * 16) ^ swz));
        const int kk = kk0 + k2 * 32;
        bf16x8 fR = *(const bf16x8*)(bR + kk);
        bf16x8 fZ = *(const bf16x8*)(bZ + kk);
        bf16x8 fN = *(const bf16x8*)(bN + kk);
#pragma unroll
        for (int mt = 0; mt < 8; ++mt) {
            accR[mt] = __builtin_amdgcn_mfma_f32_16x16x32_bf16(a[mt], fR, accR[mt], 0, 0, 0);
            accZ[mt] = __builtin_amdgcn_mfma_f32_16x16x32_bf16(a[mt], fZ, accZ[mt], 0, 0, 0);
            accN[mt] = __builtin_amdgcn_mfma_f32_16x16x32_bf16(a[mt], fN, accN[mt], 0, 0, 0);
        }
    }
}

// ---- kernel 3: fused concat-GEMM + GRU. BM=128 nodes/block, 512 threads (8 waves).
// Wave w owns output cols {16w..16w+15} of each gate block: n-tiles w (r), 8+w (z),
// 16+w (xn, k<512), 24+w (hn, k>=512). accR/accZ accumulate xr+hr / xz+hz directly.
__global__ __launch_bounds__(512) void k_gemm_gru(const float* __restrict__ mem,
                                                  const float* __restrict__ sums,
                                                  const unsigned* __restrict__ cnt,
                                                  const short* __restrict__ bp,
                                                  const float* __restrict__ bih,
                                                  const float* __restrict__ bhh,
                                                  float* __restrict__ out) {
    __shared__ short sA[2][BM * 64];
    __shared__ float sInd[BM], sInv[BM];
    const int tid = threadIdx.x;
    const int node0 = blockIdx.x * BM;

    if (tid < BM) {
        int node = node0 + tid;
        unsigned c = (node < N_NODES) ? cnt[node] : 0u;
        sInd[tid] = (c > 0u) ? 1.f : 0.f;
        sInv[tid] = 1.f / (float)(c > 1u ? c : 1u);
    }
    __syncthreads();

    const int row_ = tid >> 3;   // 0..63 ; second slot row = row_+64
    const int cg = tid & 7;

    const int l = tid & 63, w = tid >> 6;
    const int lr = l & 15, lk = l >> 4;
    const int swz = (lr & 7) << 4;

    f32x4 accR[8], accZ[8], accNx[8], accNh[8];
#pragma unroll
    for (int mt = 0; mt < 8; ++mt) {
        accR[mt] = (f32x4){0.f, 0.f, 0.f, 0.f};
        accZ[mt] = (f32x4){0.f, 0.f, 0.f, 0.f};
        accNx[mt] = (f32x4){0.f, 0.f, 0.f, 0.f};
        accNh[mt] = (f32x4){0.f, 0.f, 0.f, 0.f};
    }

    const short* bR = bp + (w * 16 + lr) * KTOT + lk * 8;
    const short* bZ = bp + ((8 + w) * 16 + lr) * KTOT + lk * 8;
    const short* bX = bp + ((16 + w) * 16 + lr) * KTOT + lk * 8;
    const short* bH = bp + ((24 + w) * 16 + lr) * KTOT + lk * 8;

    // prologue: stage chunk 0
    {
        float4 v[4];
        stage_load(mem, sums, node0, row_, cg, 0, v);
        stage_write(sA[0], sInd, sInv, row_, cg, 0, v);
    }
    __syncthreads();

    int cur = 0;
    // chunks 0..7: N-gate uses xn columns (k < 512)
    for (int c = 0; c < 8; ++c) {
        float4 v[4];
        stage_load(mem, sums, node0, row_, cg, c + 1, v);
        mfma_chunk(sA[cur], lr, lk, swz, bR, bZ, bX, c * 64, accR, accZ, accNx);
        stage_write(sA[cur ^ 1], sInd, sInv, row_, cg, c + 1, v);
        __syncthreads();
        cur ^= 1;
    }
    // chunks 8..9: N-gate uses hn columns (k >= 512)
    for (int c = 8; c < 10; ++c) {
        float4 v[4];
        if (c < 9) stage_load(mem, sums, node0, row_, cg, c + 1, v);
        mfma_chunk(sA[cur], lr, lk, swz, bR, bZ, bH, c * 64, accR, accZ, accNh);
        if (c < 9) {
            stage_write(sA[cur ^ 1], sInd, sInv, row_, cg, c + 1, v);
            __syncthreads();
        }
        cur ^= 1;
    }

    // epilogue: GRU gates. C layout: col = l&15 (-> jcol), row = (l>>4)*4 + i.
    const int jcol = w * 16 + lr;
    const float br = bih[jcol] + bhh[jcol];
    const float bz = bih[128 + jcol] + bhh[128 + jcol];
    const float bxn = bih[256 + jcol];
    const float bhn = bhh[256 + jcol];
#pragma unroll
    for (int mt = 0; mt < 8; ++mt) {
#pragma unroll
        for (int i = 0; i < 4; ++i) {
            const int node = node0 + mt * 16 + lk * 4 + i;
            if (node < N_NODES) {
                const float rp = accR[mt][i] + br;
                const float zp = accZ[mt][i] + bz;
                const float xn = accNx[mt][i] + bxn;
                const float hn = accNh[mt][i] + bhn;
                const float rg = 1.f / (1.f + expf(-rp));
                const float zg = 1.f / (1.f + expf(-zp));
                const float ng = tanhf(xn + rg * hn);
                const float mo = mem[node * D + jcol];
                out[node * D + jcol] = (1.f - zg) * ng + zg * mo;
            }
        }
    }
}

// ---- kernel 4: last_update writeout (as float values) ----
__global__ __launch_bounds__(256) void k_last(const int* __restrict__ lastmax,
                                              float* __restrict__ o) {
    int n = blockIdx.x * blockDim.x + threadIdx.x;
    if (n < N_NODES) o[n] = (float)lastmax[n];
}

extern "C" void kernel_launch(void* const* d_in, const int* in_sizes, int n_in,
                              void* d_out, int out_size, void* d_ws, size_t ws_size,
                              hipStream_t stream) {
    const float* memory      = (const float*)d_in[0];
    const int*   last_update = (const int*)d_in[1];
    const int*   src         = (const int*)d_in[2];
    const int*   dst         = (const int*)d_in[3];
    const int*   t           = (const int*)d_in[4];
    const float* raw_msg     = (const float*)d_in[5];
    const float* time_w      = (const float*)d_in[6];
    const float* time_b      = (const float*)d_in[7];
    const float* w_ih        = (const float*)d_in[8];
    const float* w_hh        = (const float*)d_in[9];
    const float* b_ih        = (const float*)d_in[10];
    const float* b_hh        = (const float*)d_in[11];

    float* out = (float*)d_out;
    char* ws = (char*)d_ws;
    float*    sums    = (float*)(ws);
    unsigned* cnt     = (unsigned*)(ws + OFF_CNT);
    int*      lastmax = (int*)(ws + OFF_LAST);
    short*    bpw     = (short*)(ws + OFF_BP);

    k_init<<<2048, 256, 0, stream>>>((float4*)ws, w_ih, w_hh, bpw);
    k_scatter<<<N_EVENTS, 128, 0, stream>>>(memory, last_update, src, dst, t,
                                            raw_msg, time_w, time_b,
                                            sums, cnt, lastmax);
    k_gemm_gru<<<(N_NODES + BM - 1) / BM, 512, 0, stream>>>(memory, sums, cnt, bpw,
                                                            b_ih, b_hh, out);
    k_last<<<(N_NODES + 255) / 256, 256, 0, stream>>>(lastmax, out + N_NODES * D);
}